// Round 18
// baseline (78.448 us; speedup 1.0000x reference)
//
#include <hip/hip_runtime.h>
#include <math.h>

// Problem constants (fixed by the reference's setup_inputs)
constexpr int B = 2, G = 8, D = 16, H = 256, W = 320;
constexpr int HW = H * W;
constexpr float EPS = 1e-5f;
constexpr int WSTRIDE = 320;   // floats per folded-weight block (P at 0, S at WSTRIDE)

typedef _Float16 h2 __attribute__((ext_vector_type(2)));

#if __has_builtin(__builtin_amdgcn_fdot2)
#define FDOT2(a, b, c) __builtin_amdgcn_fdot2((a), (b), (c), false)
#else
#define FDOT2(a, b, c) fmaf((float)(a).x, (float)(b).x, fmaf((float)(a).y, (float)(b).y, (c)))
#endif

// one-instruction pack of 2 floats -> 2 f16 (v_cvt_pkrtz_f16_f32);
// builtin returns __fp16x2, distinct type from _Float16x2 -> bit_cast
static __device__ __forceinline__ h2 cvtpk_(float a, float b) {
#if __has_builtin(__builtin_amdgcn_cvt_pkrtz)
    return __builtin_bit_cast(h2, __builtin_amdgcn_cvt_pkrtz(a, b));
#else
    h2 v; v.x = (_Float16)a; v.y = (_Float16)b; return v;
#endif
}

__device__ __forceinline__ float sigmoidf_(float x) {
    return 1.0f / (1.0f + __expf(-x));
}

__device__ __forceinline__ int reflect_(int i, int n) {
    return i < 0 ? -i : (i >= n ? 2 * n - 2 - i : i);
}

// ---------------------------------------------------------------------------
// k_prep: fold BN into weights and pack as f16 pairs (h2) for v_dot2.
// Layout per net (float-slot stride WSTRIDE):
//   h2 W0h[64]  at slots [0,64)    : 16 outputs x 4 pairs (8 in-ch)
//   h2 W1h[64]  at slots [64,128)  : 8 outputs x 8 pairs (16 in-ch)
//   h2 W2h[4]   at slots [128,132) : 1 output x 4 pairs (8 in-ch)
//   f32 B0[16]  at [132,148), B1[8] at [148,156), bias2 at [156]
// ---------------------------------------------------------------------------
__device__ __forceinline__ void pack_net_(
    const float* __restrict__ w0, const float* __restrict__ g0, const float* __restrict__ b0,
    const float* __restrict__ w1, const float* __restrict__ g1, const float* __restrict__ b1,
    const float* __restrict__ w2, const float* __restrict__ bias2,
    float* __restrict__ o, int t, float rs)
{
    if (t < 64) {
        const int oo = t >> 2, j = t & 3;
        const float s = g0[oo] * rs;
        h2 v; v.x = (_Float16)(w0[oo * 8 + 2 * j] * s);
        v.y = (_Float16)(w0[oo * 8 + 2 * j + 1] * s);
        ((h2*)o)[t] = v;
    } else if (t < 128) {
        const int u = t - 64, oo = u >> 3, j = u & 7;
        const float s = g1[oo] * rs;
        h2 v; v.x = (_Float16)(w1[oo * 16 + 2 * j] * s);
        v.y = (_Float16)(w1[oo * 16 + 2 * j + 1] * s);
        ((h2*)o)[t] = v;
    } else if (t < 132) {
        const int u = t - 128;
        h2 v; v.x = (_Float16)w2[2 * u];
        v.y = (_Float16)w2[2 * u + 1];
        ((h2*)o)[t] = v;
    } else if (t < 148) {
        o[t] = b0[t - 132];
    } else if (t < 156) {
        o[t] = b1[t - 148];
    } else if (t == 156) {
        o[t] = bias2[0];
    }
}

__global__ __launch_bounds__(256) void k_prep(
    const float* __restrict__ sw0, const float* __restrict__ sg0, const float* __restrict__ sb0,
    const float* __restrict__ sw1, const float* __restrict__ sg1, const float* __restrict__ sb1,
    const float* __restrict__ sw2, const float* __restrict__ sbias2,
    const float* __restrict__ pw0, const float* __restrict__ pg0, const float* __restrict__ pb0,
    const float* __restrict__ pw1, const float* __restrict__ pg1, const float* __restrict__ pb1,
    const float* __restrict__ pw2, const float* __restrict__ pbias2,
    float* __restrict__ wbuf)
{
    const int t = threadIdx.x;
    const float rs = rsqrtf(1.0f + EPS);
    pack_net_(pw0, pg0, pb0, pw1, pg1, pb1, pw2, pbias2, wbuf, t, rs);
    pack_net_(sw0, sg0, sb0, sw1, sg1, sb1, sw2, sbias2, wbuf + WSTRIDE, t, rs);
}

// ---------------------------------------------------------------------------
// MLP 8->16(ReLU)->8(ReLU)->1 via dot2 + cvt_pkrtz packing + packed ReLU.
// relu(cvt(x)) == cvt(relu(x)) (monotone, cvt(0)=0) -> ReLU done packed.
// ---------------------------------------------------------------------------
__device__ __forceinline__ float mlph_(const float* __restrict__ Wb, const h2 xh[4])
{
    const h2* __restrict__ W0 = (const h2*)Wb;
    const h2* __restrict__ W1 = (const h2*)Wb + 64;
    const h2* __restrict__ W2 = (const h2*)Wb + 128;
    const float* __restrict__ B0 = Wb + 132;
    const float* __restrict__ B1 = Wb + 148;
    const h2 zz = {};

    h2 l1h[8];
    #pragma unroll
    for (int o = 0; o < 8; ++o) {
        float a0 = B0[2 * o], a1 = B0[2 * o + 1];
        #pragma unroll
        for (int j = 0; j < 4; ++j) {
            a0 = FDOT2(W0[(2 * o) * 4 + j], xh[j], a0);
            a1 = FDOT2(W0[(2 * o + 1) * 4 + j], xh[j], a1);
        }
        l1h[o] = __builtin_elementwise_max(cvtpk_(a0, a1), zz);
    }
    h2 l2h[4];
    #pragma unroll
    for (int o = 0; o < 4; ++o) {
        float a0 = B1[2 * o], a1 = B1[2 * o + 1];
        #pragma unroll
        for (int j = 0; j < 8; ++j) {
            a0 = FDOT2(W1[(2 * o) * 8 + j], l1h[j], a0);
            a1 = FDOT2(W1[(2 * o + 1) * 8 + j], l1h[j], a1);
        }
        l2h[o] = __builtin_elementwise_max(cvtpk_(a0, a1), zz);
    }
    float h = Wb[156];
    #pragma unroll
    for (int j = 0; j < 4; ++j) h = FDOT2(W2[j], l2h[j], h);
    return h;
}

// ---------------------------------------------------------------------------
// Fused: PixelwiseNet + max-over-D + SimilarityNet, ONE read of x1.
// Block = 1024 threads = 64 consecutive pixels x 16 depths, one (pixel,depth)
// per thread (round-8 structure + cvt_pkrtz MLP, measured ~31 us).
// ---------------------------------------------------------------------------
__global__ __launch_bounds__(1024, 8) void k_fused(
    const float* __restrict__ x1,
    const float* __restrict__ depth_sample,
    const float* __restrict__ depth_min, const float* __restrict__ depth_max,
    const float* __restrict__ wP, const float* __restrict__ wS,
    float* __restrict__ s_out, float* __restrict__ xn_out)
{
    __shared__ float red[16][64];

    const int tid = threadIdx.x;
    const int pi = tid & 63;
    const int dt = tid >> 6;
    const int pid = blockIdx.x * 64 + pi;
    const int b = pid / HW;
    const int p = pid - b * HW;

    const float* xp = x1 + ((size_t)(b * G * D) + dt) * HW + p;
    float x[8];
    #pragma unroll
    for (int g = 0; g < 8; ++g) x[g] = xp[(size_t)g * D * HW];
    h2 xh[4];
    #pragma unroll
    for (int j = 0; j < 4; ++j) xh[j] = cvtpk_(x[2 * j], x[2 * j + 1]);

    red[dt][pi] = mlph_(wP, xh);
    __syncthreads();

    float mx = red[0][pi];
    #pragma unroll
    for (int k = 1; k < 16; ++k) mx = fmaxf(mx, red[k][pi]);
    const float vw = sigmoidf_(mx);

    h2 vwh; vwh.x = (_Float16)vw; vwh.y = (_Float16)vw;
    h2 xsh[4];
    #pragma unroll
    for (int j = 0; j < 4; ++j) xsh[j] = xh[j] * vwh;
    const float hS = mlph_(wS, xsh);

    const size_t oidx = (size_t)(b * D + dt) * HW + p;
    s_out[oidx] = hS;

    const float inv_min = 1.0f / depth_min[b];
    const float inv_max = 1.0f / depth_max[b];
    const float rinv = 1.0f / (inv_min - inv_max);
    const float ds = depth_sample[oidx];
    xn_out[oidx] = (1.0f / ds - inv_max) * rinv;
}

// ---------------------------------------------------------------------------
// k_score_depth: 1024 threads = 64 px x 16 depths, one depth/thread.
// LINEAR block id (XCD swizzle REMOVED): k_fused wrote s/xn with linear
// block->XCD round-robin, so matching linear consumption aligns the
// center/same-row taps + ds re-read with the producing XCD's L2.
// ---------------------------------------------------------------------------
__global__ __launch_bounds__(1024, 8) void k_score_depth(
    const float* __restrict__ s_arr, const float* __restrict__ xn,
    const float* __restrict__ offset, const float* __restrict__ depth_sample,
    float* __restrict__ out)
{
    __shared__ float off_lds[18][64];
    __shared__ float redM[16][64];
    __shared__ float redS[16][64];
    __shared__ float redA[16][64];

    const int wg = blockIdx.x;             // linear (producer-aligned)

    const int tid = threadIdx.x;
    const int pi = tid & 63;
    const int dt = tid >> 6;
    const int pg0_ = wg * 64;
    const int b = pg0_ / HW;
    const int pb0 = pg0_ - b * HW;
    const int p = pb0 + pi;
    const int h = p / W;
    const int w = p - h * W;

    const float* ob = offset + (size_t)b * 18 * HW + pb0;
    for (int idx = tid; idx < 18 * 64; idx += 1024) {
        const int s = idx >> 6, qq = idx & 63;
        off_lds[s][qq] = ob[(size_t)s * HW + qq];
    }
    __syncthreads();

    int a1s[9], a2s[9];
    {
        int ry1[3], ry2[3], cx1[3], cx2[3];
        #pragma unroll
        for (int i = 0; i < 3; ++i) {
            ry1[i] = reflect_(h + (i - 1) * 2, H) * W;
            ry2[i] = reflect_(h + (i - 1) * 4, H) * W;
            cx1[i] = reflect_(w + (i - 1) * 2, W);
            cx2[i] = reflect_(w + (i - 1) * 4, W);
        }
        #pragma unroll
        for (int s = 0; s < 9; ++s) {
            a1s[s] = ry1[s / 3] + cx1[s % 3];
            a2s[s] = ry2[s / 3] + cx2[s % 3];
        }
    }

    const size_t bbase = (size_t)b * D * HW;
    const float* sd = s_arr + bbase + (size_t)dt * HW;
    const float* xd = xn + bbase + (size_t)dt * HW;

    float accs = 0.0f, accx = 0.0f;
    #pragma unroll
    for (int s = 0; s < 9; ++s) {
        const float w1 = off_lds[s + 9][pi];
        const float w2 = off_lds[s][pi];
        accs += 0.5f * (w1 * sd[a1s[s]] + w2 * sd[a2s[s]]);
        accx += 0.5f * (w1 * xd[a1s[s]] + w2 * xd[a2s[s]]);
    }
    const float xc = xd[p];
    const float diff = fminf(fabsf(accx - xc) * 40.0f, 4.0f);
    const float dwv = sigmoidf_((2.0f - diff) * 2.0f);
    const float score = accs * dwv;
    const float dsv = depth_sample[bbase + (size_t)dt * HW + p];

    redM[dt][pi] = score;
    __syncthreads();
    float m = redM[0][pi];
    #pragma unroll
    for (int k = 1; k < 16; ++k) m = fmaxf(m, redM[k][pi]);

    const float e = __expf(score - m);
    redS[dt][pi] = e;
    redA[dt][pi] = dsv * e;
    __syncthreads();

    if (dt == 0) {
        float sum = 0.0f, acc = 0.0f;
        #pragma unroll
        for (int k = 0; k < 16; ++k) { sum += redS[k][pi]; acc += redA[k][pi]; }
        out[pg0_ + pi] = acc / sum;
    }
}

// ---------------------------------------------------------------------------
extern "C" void kernel_launch(void* const* d_in, const int* in_sizes, int n_in,
                              void* d_out, int out_size, void* d_ws, size_t ws_size,
                              hipStream_t stream)
{
    const float* x1           = (const float*)d_in[0];
    const float* offset       = (const float*)d_in[1];
    const float* depth_sample = (const float*)d_in[2];
    const float* depth_min    = (const float*)d_in[3];
    const float* depth_max    = (const float*)d_in[4];
    const float* s_w0 = (const float*)d_in[5];
    const float* s_g0 = (const float*)d_in[6];
    const float* s_b0 = (const float*)d_in[7];
    const float* s_w1 = (const float*)d_in[8];
    const float* s_g1 = (const float*)d_in[9];
    const float* s_b1 = (const float*)d_in[10];
    const float* s_w2 = (const float*)d_in[11];
    const float* s_bias2 = (const float*)d_in[12];
    const float* p_w0 = (const float*)d_in[13];
    const float* p_g0 = (const float*)d_in[14];
    const float* p_b0 = (const float*)d_in[15];
    const float* p_w1 = (const float*)d_in[16];
    const float* p_g1 = (const float*)d_in[17];
    const float* p_b1 = (const float*)d_in[18];
    const float* p_w2 = (const float*)d_in[19];
    const float* p_bias2 = (const float*)d_in[20];

    float* s_arr = (float*)d_ws;                         // B*D*HW
    float* xn    = s_arr + (size_t)B * D * HW;           // B*D*HW
    float* wbuf  = xn + (size_t)B * D * HW;              // 2*WSTRIDE floats

    k_prep<<<1, 256, 0, stream>>>(
        s_w0, s_g0, s_b0, s_w1, s_g1, s_b1, s_w2, s_bias2,
        p_w0, p_g0, p_b0, p_w1, p_g1, p_b1, p_w2, p_bias2, wbuf);

    k_fused<<<(B * HW) / 64, 1024, 0, stream>>>(
        x1, depth_sample, depth_min, depth_max,
        wbuf, wbuf + WSTRIDE, s_arr, xn);

    k_score_depth<<<(B * HW) / 64, 1024, 0, stream>>>(
        s_arr, xn, offset, depth_sample, (float*)d_out);
}

// Round 19
// 70.747 us; speedup vs baseline: 1.1089x; 1.1089x over previous
//
#include <hip/hip_runtime.h>
#include <math.h>

// Problem constants (fixed by the reference's setup_inputs)
constexpr int B = 2, G = 8, D = 16, H = 256, W = 320;
constexpr int HW = H * W;
constexpr float EPS = 1e-5f;
constexpr int WSTRIDE = 320;   // floats per folded-weight block (P at 0, S at WSTRIDE)

typedef _Float16 h2 __attribute__((ext_vector_type(2)));

#if __has_builtin(__builtin_amdgcn_fdot2)
#define FDOT2(a, b, c) __builtin_amdgcn_fdot2((a), (b), (c), false)
#else
#define FDOT2(a, b, c) fmaf((float)(a).x, (float)(b).x, fmaf((float)(a).y, (float)(b).y, (c)))
#endif

// one-instruction pack of 2 floats -> 2 f16 (v_cvt_pkrtz_f16_f32);
// builtin returns __fp16x2, distinct type from _Float16x2 -> bit_cast
static __device__ __forceinline__ h2 cvtpk_(float a, float b) {
#if __has_builtin(__builtin_amdgcn_cvt_pkrtz)
    return __builtin_bit_cast(h2, __builtin_amdgcn_cvt_pkrtz(a, b));
#else
    h2 v; v.x = (_Float16)a; v.y = (_Float16)b; return v;
#endif
}

__device__ __forceinline__ float sigmoidf_(float x) {
    return 1.0f / (1.0f + __expf(-x));
}

__device__ __forceinline__ int reflect_(int i, int n) {
    return i < 0 ? -i : (i >= n ? 2 * n - 2 - i : i);
}

// ---------------------------------------------------------------------------
// k_prep: fold BN into weights and pack as f16 pairs (h2) for v_dot2.
// Layout per net (float-slot stride WSTRIDE):
//   h2 W0h[64]  at slots [0,64)    : 16 outputs x 4 pairs (8 in-ch)
//   h2 W1h[64]  at slots [64,128)  : 8 outputs x 8 pairs (16 in-ch)
//   h2 W2h[4]   at slots [128,132) : 1 output x 4 pairs (8 in-ch)
//   f32 B0[16]  at [132,148), B1[8] at [148,156), bias2 at [156]
// ---------------------------------------------------------------------------
__device__ __forceinline__ void pack_net_(
    const float* __restrict__ w0, const float* __restrict__ g0, const float* __restrict__ b0,
    const float* __restrict__ w1, const float* __restrict__ g1, const float* __restrict__ b1,
    const float* __restrict__ w2, const float* __restrict__ bias2,
    float* __restrict__ o, int t, float rs)
{
    if (t < 64) {
        const int oo = t >> 2, j = t & 3;
        const float s = g0[oo] * rs;
        h2 v; v.x = (_Float16)(w0[oo * 8 + 2 * j] * s);
        v.y = (_Float16)(w0[oo * 8 + 2 * j + 1] * s);
        ((h2*)o)[t] = v;
    } else if (t < 128) {
        const int u = t - 64, oo = u >> 3, j = u & 7;
        const float s = g1[oo] * rs;
        h2 v; v.x = (_Float16)(w1[oo * 16 + 2 * j] * s);
        v.y = (_Float16)(w1[oo * 16 + 2 * j + 1] * s);
        ((h2*)o)[t] = v;
    } else if (t < 132) {
        const int u = t - 128;
        h2 v; v.x = (_Float16)w2[2 * u];
        v.y = (_Float16)w2[2 * u + 1];
        ((h2*)o)[t] = v;
    } else if (t < 148) {
        o[t] = b0[t - 132];
    } else if (t < 156) {
        o[t] = b1[t - 148];
    } else if (t == 156) {
        o[t] = bias2[0];
    }
}

__global__ __launch_bounds__(256) void k_prep(
    const float* __restrict__ sw0, const float* __restrict__ sg0, const float* __restrict__ sb0,
    const float* __restrict__ sw1, const float* __restrict__ sg1, const float* __restrict__ sb1,
    const float* __restrict__ sw2, const float* __restrict__ sbias2,
    const float* __restrict__ pw0, const float* __restrict__ pg0, const float* __restrict__ pb0,
    const float* __restrict__ pw1, const float* __restrict__ pg1, const float* __restrict__ pb1,
    const float* __restrict__ pw2, const float* __restrict__ pbias2,
    float* __restrict__ wbuf)
{
    const int t = threadIdx.x;
    const float rs = rsqrtf(1.0f + EPS);
    pack_net_(pw0, pg0, pb0, pw1, pg1, pb1, pw2, pbias2, wbuf, t, rs);
    pack_net_(sw0, sg0, sb0, sw1, sg1, sb1, sw2, sbias2, wbuf + WSTRIDE, t, rs);
}

// ---------------------------------------------------------------------------
// MLP 8->16(ReLU)->8(ReLU)->1 via dot2 + cvt_pkrtz packing + packed ReLU.
// relu(cvt(x)) == cvt(relu(x)) (monotone, cvt(0)=0) -> ReLU done packed.
// ---------------------------------------------------------------------------
__device__ __forceinline__ float mlph_(const float* __restrict__ Wb, const h2 xh[4])
{
    const h2* __restrict__ W0 = (const h2*)Wb;
    const h2* __restrict__ W1 = (const h2*)Wb + 64;
    const h2* __restrict__ W2 = (const h2*)Wb + 128;
    const float* __restrict__ B0 = Wb + 132;
    const float* __restrict__ B1 = Wb + 148;
    const h2 zz = {};

    h2 l1h[8];
    #pragma unroll
    for (int o = 0; o < 8; ++o) {
        float a0 = B0[2 * o], a1 = B0[2 * o + 1];
        #pragma unroll
        for (int j = 0; j < 4; ++j) {
            a0 = FDOT2(W0[(2 * o) * 4 + j], xh[j], a0);
            a1 = FDOT2(W0[(2 * o + 1) * 4 + j], xh[j], a1);
        }
        l1h[o] = __builtin_elementwise_max(cvtpk_(a0, a1), zz);
    }
    h2 l2h[4];
    #pragma unroll
    for (int o = 0; o < 4; ++o) {
        float a0 = B1[2 * o], a1 = B1[2 * o + 1];
        #pragma unroll
        for (int j = 0; j < 8; ++j) {
            a0 = FDOT2(W1[(2 * o) * 8 + j], l1h[j], a0);
            a1 = FDOT2(W1[(2 * o + 1) * 8 + j], l1h[j], a1);
        }
        l2h[o] = __builtin_elementwise_max(cvtpk_(a0, a1), zz);
    }
    float h = Wb[156];
    #pragma unroll
    for (int j = 0; j < 4; ++j) h = FDOT2(W2[j], l2h[j], h);
    return h;
}

// ---------------------------------------------------------------------------
// Fused: PixelwiseNet + max-over-D + SimilarityNet, ONE read of x1.
// Block = 1024 threads = 64 consecutive pixels x 16 depths, one (pixel,depth)
// per thread (round-8 proven structure + cvt_pkrtz MLP, measured ~31 us).
// ---------------------------------------------------------------------------
__global__ __launch_bounds__(1024, 8) void k_fused(
    const float* __restrict__ x1,
    const float* __restrict__ depth_sample,
    const float* __restrict__ depth_min, const float* __restrict__ depth_max,
    const float* __restrict__ wP, const float* __restrict__ wS,
    float* __restrict__ s_out, float* __restrict__ xn_out)
{
    __shared__ float red[16][64];

    const int tid = threadIdx.x;
    const int pi = tid & 63;
    const int dt = tid >> 6;
    const int pid = blockIdx.x * 64 + pi;
    const int b = pid / HW;
    const int p = pid - b * HW;

    const float* xp = x1 + ((size_t)(b * G * D) + dt) * HW + p;
    float x[8];
    #pragma unroll
    for (int g = 0; g < 8; ++g) x[g] = xp[(size_t)g * D * HW];
    h2 xh[4];
    #pragma unroll
    for (int j = 0; j < 4; ++j) xh[j] = cvtpk_(x[2 * j], x[2 * j + 1]);

    red[dt][pi] = mlph_(wP, xh);
    __syncthreads();

    float mx = red[0][pi];
    #pragma unroll
    for (int k = 1; k < 16; ++k) mx = fmaxf(mx, red[k][pi]);
    const float vw = sigmoidf_(mx);

    h2 vwh; vwh.x = (_Float16)vw; vwh.y = (_Float16)vw;
    h2 xsh[4];
    #pragma unroll
    for (int j = 0; j < 4; ++j) xsh[j] = xh[j] * vwh;
    const float hS = mlph_(wS, xsh);

    const size_t oidx = (size_t)(b * D + dt) * HW + p;
    s_out[oidx] = hS;

    const float inv_min = 1.0f / depth_min[b];
    const float inv_max = 1.0f / depth_max[b];
    const float rinv = 1.0f / (inv_min - inv_max);
    const float ds = depth_sample[oidx];
    xn_out[oidx] = (1.0f / ds - inv_max) * rinv;
}

// ---------------------------------------------------------------------------
// k_score_depth: 1024 threads = 64 px x 16 depths, one depth/thread.
// Bijective XCD swizzle (nwg = 2560 = 8*320). ROUND-15 PROVEN config
// (swizzle removal measured -8 us regression; interleave measured -4 us).
// ---------------------------------------------------------------------------
__global__ __launch_bounds__(1024, 8) void k_score_depth(
    const float* __restrict__ s_arr, const float* __restrict__ xn,
    const float* __restrict__ offset, const float* __restrict__ depth_sample,
    float* __restrict__ out)
{
    __shared__ float off_lds[18][64];
    __shared__ float redM[16][64];
    __shared__ float redS[16][64];
    __shared__ float redA[16][64];

    const int bid = blockIdx.x;
    const int wg = (bid & 7) * 320 + (bid >> 3);

    const int tid = threadIdx.x;
    const int pi = tid & 63;
    const int dt = tid >> 6;
    const int pg0_ = wg * 64;
    const int b = pg0_ / HW;
    const int pb0 = pg0_ - b * HW;
    const int p = pb0 + pi;
    const int h = p / W;
    const int w = p - h * W;

    const float* ob = offset + (size_t)b * 18 * HW + pb0;
    for (int idx = tid; idx < 18 * 64; idx += 1024) {
        const int s = idx >> 6, qq = idx & 63;
        off_lds[s][qq] = ob[(size_t)s * HW + qq];
    }
    __syncthreads();

    int a1s[9], a2s[9];
    {
        int ry1[3], ry2[3], cx1[3], cx2[3];
        #pragma unroll
        for (int i = 0; i < 3; ++i) {
            ry1[i] = reflect_(h + (i - 1) * 2, H) * W;
            ry2[i] = reflect_(h + (i - 1) * 4, H) * W;
            cx1[i] = reflect_(w + (i - 1) * 2, W);
            cx2[i] = reflect_(w + (i - 1) * 4, W);
        }
        #pragma unroll
        for (int s = 0; s < 9; ++s) {
            a1s[s] = ry1[s / 3] + cx1[s % 3];
            a2s[s] = ry2[s / 3] + cx2[s % 3];
        }
    }

    const size_t bbase = (size_t)b * D * HW;
    const float* sd = s_arr + bbase + (size_t)dt * HW;
    const float* xd = xn + bbase + (size_t)dt * HW;

    float accs = 0.0f, accx = 0.0f;
    #pragma unroll
    for (int s = 0; s < 9; ++s) {
        const float w1 = off_lds[s + 9][pi];
        const float w2 = off_lds[s][pi];
        accs += 0.5f * (w1 * sd[a1s[s]] + w2 * sd[a2s[s]]);
        accx += 0.5f * (w1 * xd[a1s[s]] + w2 * xd[a2s[s]]);
    }
    const float xc = xd[p];
    const float diff = fminf(fabsf(accx - xc) * 40.0f, 4.0f);
    const float dwv = sigmoidf_((2.0f - diff) * 2.0f);
    const float score = accs * dwv;
    const float dsv = depth_sample[bbase + (size_t)dt * HW + p];

    redM[dt][pi] = score;
    __syncthreads();
    float m = redM[0][pi];
    #pragma unroll
    for (int k = 1; k < 16; ++k) m = fmaxf(m, redM[k][pi]);

    const float e = __expf(score - m);
    redS[dt][pi] = e;
    redA[dt][pi] = dsv * e;
    __syncthreads();

    if (dt == 0) {
        float sum = 0.0f, acc = 0.0f;
        #pragma unroll
        for (int k = 0; k < 16; ++k) { sum += redS[k][pi]; acc += redA[k][pi]; }
        out[pg0_ + pi] = acc / sum;
    }
}

// ---------------------------------------------------------------------------
extern "C" void kernel_launch(void* const* d_in, const int* in_sizes, int n_in,
                              void* d_out, int out_size, void* d_ws, size_t ws_size,
                              hipStream_t stream)
{
    const float* x1           = (const float*)d_in[0];
    const float* offset       = (const float*)d_in[1];
    const float* depth_sample = (const float*)d_in[2];
    const float* depth_min    = (const float*)d_in[3];
    const float* depth_max    = (const float*)d_in[4];
    const float* s_w0 = (const float*)d_in[5];
    const float* s_g0 = (const float*)d_in[6];
    const float* s_b0 = (const float*)d_in[7];
    const float* s_w1 = (const float*)d_in[8];
    const float* s_g1 = (const float*)d_in[9];
    const float* s_b1 = (const float*)d_in[10];
    const float* s_w2 = (const float*)d_in[11];
    const float* s_bias2 = (const float*)d_in[12];
    const float* p_w0 = (const float*)d_in[13];
    const float* p_g0 = (const float*)d_in[14];
    const float* p_b0 = (const float*)d_in[15];
    const float* p_w1 = (const float*)d_in[16];
    const float* p_g1 = (const float*)d_in[17];
    const float* p_b1 = (const float*)d_in[18];
    const float* p_w2 = (const float*)d_in[19];
    const float* p_bias2 = (const float*)d_in[20];

    float* s_arr = (float*)d_ws;                         // B*D*HW
    float* xn    = s_arr + (size_t)B * D * HW;           // B*D*HW
    float* wbuf  = xn + (size_t)B * D * HW;              // 2*WSTRIDE floats

    k_prep<<<1, 256, 0, stream>>>(
        s_w0, s_g0, s_b0, s_w1, s_g1, s_b1, s_w2, s_bias2,
        p_w0, p_g0, p_b0, p_w1, p_g1, p_b1, p_w2, p_bias2, wbuf);

    k_fused<<<(B * HW) / 64, 1024, 0, stream>>>(
        x1, depth_sample, depth_min, depth_max,
        wbuf, wbuf + WSTRIDE, s_arr, xn);

    k_score_depth<<<(B * HW) / 64, 1024, 0, stream>>>(
        s_arr, xn, offset, depth_sample, (float*)d_out);
}

// Round 20
// 68.312 us; speedup vs baseline: 1.1484x; 1.0356x over previous
//
#include <hip/hip_runtime.h>
#include <math.h>

// Problem constants (fixed by the reference's setup_inputs)
constexpr int B = 2, G = 8, D = 16, H = 256, W = 320;
constexpr int HW = H * W;
constexpr float EPS = 1e-5f;
constexpr int WSTRIDE = 320;   // floats per folded-weight block (P at 0, S at WSTRIDE)

typedef _Float16 h2 __attribute__((ext_vector_type(2)));

#if __has_builtin(__builtin_amdgcn_fdot2)
#define FDOT2(a, b, c) __builtin_amdgcn_fdot2((a), (b), (c), false)
#else
#define FDOT2(a, b, c) fmaf((float)(a).x, (float)(b).x, fmaf((float)(a).y, (float)(b).y, (c)))
#endif

// one-instruction pack of 2 floats -> 2 f16 (v_cvt_pkrtz_f16_f32);
// builtin returns __fp16x2, distinct type from _Float16x2 -> bit_cast
static __device__ __forceinline__ h2 cvtpk_(float a, float b) {
#if __has_builtin(__builtin_amdgcn_cvt_pkrtz)
    return __builtin_bit_cast(h2, __builtin_amdgcn_cvt_pkrtz(a, b));
#else
    h2 v; v.x = (_Float16)a; v.y = (_Float16)b; return v;
#endif
}

__device__ __forceinline__ float sigmoidf_(float x) {
    return 1.0f / (1.0f + __expf(-x));
}

__device__ __forceinline__ int reflect_(int i, int n) {
    return i < 0 ? -i : (i >= n ? 2 * n - 2 - i : i);
}

// ---------------------------------------------------------------------------
// k_prep: fold BN into weights and pack as f16 pairs (h2) for v_dot2.
// Layout per net (float-slot stride WSTRIDE):
//   h2 W0h[64]  at slots [0,64)    : 16 outputs x 4 pairs (8 in-ch)
//   h2 W1h[64]  at slots [64,128)  : 8 outputs x 8 pairs (16 in-ch)
//   h2 W2h[4]   at slots [128,132) : 1 output x 4 pairs (8 in-ch)
//   f32 B0[16]  at [132,148), B1[8] at [148,156), bias2 at [156]
// ---------------------------------------------------------------------------
__device__ __forceinline__ void pack_net_(
    const float* __restrict__ w0, const float* __restrict__ g0, const float* __restrict__ b0,
    const float* __restrict__ w1, const float* __restrict__ g1, const float* __restrict__ b1,
    const float* __restrict__ w2, const float* __restrict__ bias2,
    float* __restrict__ o, int t, float rs)
{
    if (t < 64) {
        const int oo = t >> 2, j = t & 3;
        const float s = g0[oo] * rs;
        h2 v; v.x = (_Float16)(w0[oo * 8 + 2 * j] * s);
        v.y = (_Float16)(w0[oo * 8 + 2 * j + 1] * s);
        ((h2*)o)[t] = v;
    } else if (t < 128) {
        const int u = t - 64, oo = u >> 3, j = u & 7;
        const float s = g1[oo] * rs;
        h2 v; v.x = (_Float16)(w1[oo * 16 + 2 * j] * s);
        v.y = (_Float16)(w1[oo * 16 + 2 * j + 1] * s);
        ((h2*)o)[t] = v;
    } else if (t < 132) {
        const int u = t - 128;
        h2 v; v.x = (_Float16)w2[2 * u];
        v.y = (_Float16)w2[2 * u + 1];
        ((h2*)o)[t] = v;
    } else if (t < 148) {
        o[t] = b0[t - 132];
    } else if (t < 156) {
        o[t] = b1[t - 148];
    } else if (t == 156) {
        o[t] = bias2[0];
    }
}

__global__ __launch_bounds__(256) void k_prep(
    const float* __restrict__ sw0, const float* __restrict__ sg0, const float* __restrict__ sb0,
    const float* __restrict__ sw1, const float* __restrict__ sg1, const float* __restrict__ sb1,
    const float* __restrict__ sw2, const float* __restrict__ sbias2,
    const float* __restrict__ pw0, const float* __restrict__ pg0, const float* __restrict__ pb0,
    const float* __restrict__ pw1, const float* __restrict__ pg1, const float* __restrict__ pb1,
    const float* __restrict__ pw2, const float* __restrict__ pbias2,
    float* __restrict__ wbuf)
{
    const int t = threadIdx.x;
    const float rs = rsqrtf(1.0f + EPS);
    pack_net_(pw0, pg0, pb0, pw1, pg1, pb1, pw2, pbias2, wbuf, t, rs);
    pack_net_(sw0, sg0, sb0, sw1, sg1, sb1, sw2, sbias2, wbuf + WSTRIDE, t, rs);
}

// ---------------------------------------------------------------------------
// Dual-item MLP 8->16(ReLU)->8(ReLU)->1: two independent dot2 chains share
// every weight fetch (s_load); cvt_pkrtz packing + packed ReLU per item.
// ---------------------------------------------------------------------------
__device__ __forceinline__ float2 mlph2_(const float* __restrict__ Wb,
                                         const h2 xa[4], const h2 xb[4])
{
    const h2* __restrict__ W0 = (const h2*)Wb;
    const h2* __restrict__ W1 = (const h2*)Wb + 64;
    const h2* __restrict__ W2 = (const h2*)Wb + 128;
    const float* __restrict__ B0 = Wb + 132;
    const float* __restrict__ B1 = Wb + 148;
    const h2 zz = {};

    h2 l1a[8], l1b[8];
    #pragma unroll
    for (int o = 0; o < 8; ++o) {
        float a0 = B0[2 * o], a1 = B0[2 * o + 1];
        float c0 = a0, c1 = a1;
        #pragma unroll
        for (int j = 0; j < 4; ++j) {
            const h2 wA = W0[(2 * o) * 4 + j];
            const h2 wB = W0[(2 * o + 1) * 4 + j];
            a0 = FDOT2(wA, xa[j], a0); c0 = FDOT2(wA, xb[j], c0);
            a1 = FDOT2(wB, xa[j], a1); c1 = FDOT2(wB, xb[j], c1);
        }
        l1a[o] = __builtin_elementwise_max(cvtpk_(a0, a1), zz);
        l1b[o] = __builtin_elementwise_max(cvtpk_(c0, c1), zz);
    }
    h2 l2a[4], l2b[4];
    #pragma unroll
    for (int o = 0; o < 4; ++o) {
        float a0 = B1[2 * o], a1 = B1[2 * o + 1];
        float c0 = a0, c1 = a1;
        #pragma unroll
        for (int j = 0; j < 8; ++j) {
            const h2 wA = W1[(2 * o) * 8 + j];
            const h2 wB = W1[(2 * o + 1) * 8 + j];
            a0 = FDOT2(wA, l1a[j], a0); c0 = FDOT2(wA, l1b[j], c0);
            a1 = FDOT2(wB, l1a[j], a1); c1 = FDOT2(wB, l1b[j], c1);
        }
        l2a[o] = __builtin_elementwise_max(cvtpk_(a0, a1), zz);
        l2b[o] = __builtin_elementwise_max(cvtpk_(c0, c1), zz);
    }
    float hA = Wb[156], hB = Wb[156];
    #pragma unroll
    for (int j = 0; j < 4; ++j) {
        const h2 w = W2[j];
        hA = FDOT2(w, l2a[j], hA);
        hB = FDOT2(w, l2b[j], hB);
    }
    return make_float2(hA, hB);
}

// ---------------------------------------------------------------------------
// Fused: PixelwiseNet + max-over-D + SimilarityNet, ONE read of x1.
// Block = 512 threads = 32 pixel-pairs x 16 depths (64 consecutive px).
// Each thread: 2 adjacent pixels at 1 depth -> float2 loads/stores, every
// weight s_load feeds two independent chains (2x ILP, half the issue).
// ---------------------------------------------------------------------------
__global__ __launch_bounds__(512, 8) void k_fused(
    const float* __restrict__ x1,
    const float* __restrict__ depth_sample,
    const float* __restrict__ depth_min, const float* __restrict__ depth_max,
    const float* __restrict__ wP, const float* __restrict__ wS,
    float* __restrict__ s_out, float* __restrict__ xn_out)
{
    __shared__ float2 red[16][32];

    const int tid = threadIdx.x;
    const int pl = tid & 31;           // pixel-pair lane (32 pairs = 64 px)
    const int dt = tid >> 5;           // depth hypothesis 0..15
    const int pid0 = blockIdx.x * 64 + 2 * pl;
    const int b = pid0 / HW;
    const int p0 = pid0 - b * HW;

    const float* xp = x1 + ((size_t)(b * G * D) + dt) * HW + p0;
    float2 xv[8];
    #pragma unroll
    for (int g = 0; g < 8; ++g)
        xv[g] = *reinterpret_cast<const float2*>(xp + (size_t)g * D * HW);
    h2 xa[4], xb[4];
    #pragma unroll
    for (int j = 0; j < 4; ++j) {
        xa[j] = cvtpk_(xv[2 * j].x, xv[2 * j + 1].x);
        xb[j] = cvtpk_(xv[2 * j].y, xv[2 * j + 1].y);
    }

    red[dt][pl] = mlph2_(wP, xa, xb);
    __syncthreads();

    float2 mx = red[0][pl];
    #pragma unroll
    for (int k = 1; k < 16; ++k) {
        const float2 r = red[k][pl];
        mx.x = fmaxf(mx.x, r.x);
        mx.y = fmaxf(mx.y, r.y);
    }
    const float vwa = sigmoidf_(mx.x);
    const float vwb = sigmoidf_(mx.y);

    h2 va; va.x = (_Float16)vwa; va.y = (_Float16)vwa;
    h2 vb; vb.x = (_Float16)vwb; vb.y = (_Float16)vwb;
    h2 xsa[4], xsb[4];
    #pragma unroll
    for (int j = 0; j < 4; ++j) { xsa[j] = xa[j] * va; xsb[j] = xb[j] * vb; }
    const float2 hS = mlph2_(wS, xsa, xsb);

    const size_t oidx = (size_t)(b * D + dt) * HW + p0;
    *reinterpret_cast<float2*>(s_out + oidx) = hS;

    const float inv_min = 1.0f / depth_min[b];
    const float inv_max = 1.0f / depth_max[b];
    const float rinv = 1.0f / (inv_min - inv_max);
    const float2 ds = *reinterpret_cast<const float2*>(depth_sample + oidx);
    *reinterpret_cast<float2*>(xn_out + oidx) =
        make_float2((1.0f / ds.x - inv_max) * rinv,
                    (1.0f / ds.y - inv_max) * rinv);
}

// ---------------------------------------------------------------------------
// k_score_depth: 1024 threads = 64 px x 16 depths, one depth/thread.
// Bijective XCD swizzle (nwg = 2560 = 8*320). ROUND-15/19 PROVEN config.
// ---------------------------------------------------------------------------
__global__ __launch_bounds__(1024, 8) void k_score_depth(
    const float* __restrict__ s_arr, const float* __restrict__ xn,
    const float* __restrict__ offset, const float* __restrict__ depth_sample,
    float* __restrict__ out)
{
    __shared__ float off_lds[18][64];
    __shared__ float redM[16][64];
    __shared__ float redS[16][64];
    __shared__ float redA[16][64];

    const int bid = blockIdx.x;
    const int wg = (bid & 7) * 320 + (bid >> 3);

    const int tid = threadIdx.x;
    const int pi = tid & 63;
    const int dt = tid >> 6;
    const int pg0_ = wg * 64;
    const int b = pg0_ / HW;
    const int pb0 = pg0_ - b * HW;
    const int p = pb0 + pi;
    const int h = p / W;
    const int w = p - h * W;

    const float* ob = offset + (size_t)b * 18 * HW + pb0;
    for (int idx = tid; idx < 18 * 64; idx += 1024) {
        const int s = idx >> 6, qq = idx & 63;
        off_lds[s][qq] = ob[(size_t)s * HW + qq];
    }
    __syncthreads();

    int a1s[9], a2s[9];
    {
        int ry1[3], ry2[3], cx1[3], cx2[3];
        #pragma unroll
        for (int i = 0; i < 3; ++i) {
            ry1[i] = reflect_(h + (i - 1) * 2, H) * W;
            ry2[i] = reflect_(h + (i - 1) * 4, H) * W;
            cx1[i] = reflect_(w + (i - 1) * 2, W);
            cx2[i] = reflect_(w + (i - 1) * 4, W);
        }
        #pragma unroll
        for (int s = 0; s < 9; ++s) {
            a1s[s] = ry1[s / 3] + cx1[s % 3];
            a2s[s] = ry2[s / 3] + cx2[s % 3];
        }
    }

    const size_t bbase = (size_t)b * D * HW;
    const float* sd = s_arr + bbase + (size_t)dt * HW;
    const float* xd = xn + bbase + (size_t)dt * HW;

    float accs = 0.0f, accx = 0.0f;
    #pragma unroll
    for (int s = 0; s < 9; ++s) {
        const float w1 = off_lds[s + 9][pi];
        const float w2 = off_lds[s][pi];
        accs += 0.5f * (w1 * sd[a1s[s]] + w2 * sd[a2s[s]]);
        accx += 0.5f * (w1 * xd[a1s[s]] + w2 * xd[a2s[s]]);
    }
    const float xc = xd[p];
    const float diff = fminf(fabsf(accx - xc) * 40.0f, 4.0f);
    const float dwv = sigmoidf_((2.0f - diff) * 2.0f);
    const float score = accs * dwv;
    const float dsv = depth_sample[bbase + (size_t)dt * HW + p];

    redM[dt][pi] = score;
    __syncthreads();
    float m = redM[0][pi];
    #pragma unroll
    for (int k = 1; k < 16; ++k) m = fmaxf(m, redM[k][pi]);

    const float e = __expf(score - m);
    redS[dt][pi] = e;
    redA[dt][pi] = dsv * e;
    __syncthreads();

    if (dt == 0) {
        float sum = 0.0f, acc = 0.0f;
        #pragma unroll
        for (int k = 0; k < 16; ++k) { sum += redS[k][pi]; acc += redA[k][pi]; }
        out[pg0_ + pi] = acc / sum;
    }
}

// ---------------------------------------------------------------------------
extern "C" void kernel_launch(void* const* d_in, const int* in_sizes, int n_in,
                              void* d_out, int out_size, void* d_ws, size_t ws_size,
                              hipStream_t stream)
{
    const float* x1           = (const float*)d_in[0];
    const float* offset       = (const float*)d_in[1];
    const float* depth_sample = (const float*)d_in[2];
    const float* depth_min    = (const float*)d_in[3];
    const float* depth_max    = (const float*)d_in[4];
    const float* s_w0 = (const float*)d_in[5];
    const float* s_g0 = (const float*)d_in[6];
    const float* s_b0 = (const float*)d_in[7];
    const float* s_w1 = (const float*)d_in[8];
    const float* s_g1 = (const float*)d_in[9];
    const float* s_b1 = (const float*)d_in[10];
    const float* s_w2 = (const float*)d_in[11];
    const float* s_bias2 = (const float*)d_in[12];
    const float* p_w0 = (const float*)d_in[13];
    const float* p_g0 = (const float*)d_in[14];
    const float* p_b0 = (const float*)d_in[15];
    const float* p_w1 = (const float*)d_in[16];
    const float* p_g1 = (const float*)d_in[17];
    const float* p_b1 = (const float*)d_in[18];
    const float* p_w2 = (const float*)d_in[19];
    const float* p_bias2 = (const float*)d_in[20];

    float* s_arr = (float*)d_ws;                         // B*D*HW
    float* xn    = s_arr + (size_t)B * D * HW;           // B*D*HW
    float* wbuf  = xn + (size_t)B * D * HW;              // 2*WSTRIDE floats

    k_prep<<<1, 256, 0, stream>>>(
        s_w0, s_g0, s_b0, s_w1, s_g1, s_b1, s_w2, s_bias2,
        p_w0, p_g0, p_b0, p_w1, p_g1, p_b1, p_w2, p_bias2, wbuf);

    k_fused<<<(B * HW) / 64, 512, 0, stream>>>(
        x1, depth_sample, depth_min, depth_max,
        wbuf, wbuf + WSTRIDE, s_arr, xn);

    k_score_depth<<<(B * HW) / 64, 1024, 0, stream>>>(
        s_arr, xn, offset, depth_sample, (float*)d_out);
}